// Round 8
// baseline (732.851 us; speedup 1.0000x reference)
//
#include <hip/hip_runtime.h>
#include <hip/hip_bf16.h>
#include <math.h>

#define BATCH 128
#define TT    12
#define CIN   10
#define HID   64
#define PLANE 625
#define NU    10          // 16B channel-units per pixel (80 padded ch)
#define IPB   50000       // shorts per batch image in inp: NU*PLANE*8
#define NKB   45          // k-blocks: 9 taps * 5 chunks of 16 ch
#define CSZ   (BATCH*PLANE*HID)   // floats in c / h buffers
#define KSPLIT 10         // k_mlp1 k-dimension splits (40000/10 = 4000 per block)

typedef __attribute__((ext_vector_type(8)))  short bf16x8;
typedef __attribute__((ext_vector_type(16))) float f32x16;

__device__ __forceinline__ float fsigm(float v){ return 1.f/(1.f+__expf(-v)); }
__device__ __forceinline__ float ftanh(float v){ return 1.f - 2.f/(__expf(2.f*v)+1.f); }
__device__ __forceinline__ unsigned short f2bf(float v){
    __hip_bfloat16 b = __float2bfloat16(v);
    return *reinterpret_cast<unsigned short*>(&b);
}

// ---- prepack conv_w (256,74,3,3) f32 -> B-fragments bf16 ----
// k = tap*80 + ch (tap = ky*3+kx), n-permutation: col = jlo*4 + g  (j = nt*8+jlo, o = g*64+j)
// frag layout (32x32x16 B): lane l: col = l&31, k_local = (l>>5)*8 + e
__global__ void k_wprep(const float* __restrict__ w, unsigned short* __restrict__ wpk){
    int tid = blockIdx.x*256 + threadIdx.x;      // NKB*8*64 = 23040 total
    if (tid >= NKB*8*64) return;
    int lane = tid & 63;
    int nt   = (tid >> 6) & 7;
    int kb   = tid >> 9;
    int tap = kb/5, ci = kb - tap*5;
    int ky = tap/3, kx = tap - ky*3;
    int g = lane & 3, jlo = (lane & 31) >> 2, kh = lane >> 5;
    int o = g*64 + nt*8 + jlo;
    union { unsigned short u[8]; float4 f; } pk;
    #pragma unroll
    for (int e = 0; e < 8; ++e){
        int ch = ci*16 + kh*8 + e;
        float v = (ch < 74) ? w[((o*74 + ch)*3 + ky)*3 + kx] : 0.f;
        pk.u[e] = f2bf(v);
    }
    *reinterpret_cast<float4*>(wpk + (size_t)tid*8) = pk.f;   // idx = (kb*8+nt)*64+lane
}

// ---- copy x_0 (f32 NCHW) into inp buffer x-slots (unit-major bf16 layout) ----
// inp layout: [b][u][625 pix][8 ch-slots], u = ch>>3
__global__ void k_xcopy(const float* __restrict__ x, unsigned short* __restrict__ inp, int t){
    int idx = blockIdx.x*256 + threadIdx.x;      // 128*10*625 = 800000
    if (idx >= BATCH*CIN*PLANE) return;
    int m  = idx % PLANE;
    int r  = idx / PLANE;
    int ch = r % CIN;
    int b  = r / CIN;
    float v = x[((size_t)(b*TT + t)*CIN + ch)*PLANE + m];
    inp[(size_t)b*IPB + ((((ch>>3)*PLANE) + m)<<3) + (ch&7)] = f2bf(v);
}

// ---- fused conv-as-GEMM (MFMA bf16) + LSTM pointwise + next-step x-copy ----
// block = (mgroup of 128 m, batch), 512 thr = 8 waves; wave = n-tile of 32.
// A-tile LDS layout [u][216 pix][16B]: conflict-free ds_read_b128.
// K-loop: ci unrolled w/ immediate ds offsets; tap loop unroll-1 w/ constant pointer
// increments; B via walking pointer + 1-deep prefetch (bounds reg pressure).
// Epilogue: in-register 4x4 quad transpose -> all 64 lanes do c-updates.
__global__ __launch_bounds__(512) void k_gemm(
    const float* __restrict__ x,
    const unsigned short* __restrict__ inp,   // step-t input, unit-major
    unsigned short* __restrict__ inpn,        // next-step buffer (h-part + x-part writes)
    const unsigned short* __restrict__ wpk,
    const float* __restrict__ bias,           // conv_b[256], o = g*64+j
    float* __restrict__ cbuf,                 // [b][625][64] fp32
    float* __restrict__ hbuf,                 // [b][625][64] fp32 (written at t=TT-1)
    int t)
{
    __shared__ __align__(16) unsigned short at2[2160*8];   // [10 u][216 pix][8], 34.56 KB

    const int tid  = threadIdx.x;
    const int mg   = blockIdx.x;              // 0..4 (128 m each; m 625..639 pad)
    const int b    = blockIdx.y;
    const int lane = tid & 63;
    const int nt   = tid >> 6;                // wave id = n-tile
    const int r0row = (mg*128)/25;            // 0,5,10,15,20

    // ---- stage A-tile: rows r0row-1..r0row+6, cols -1..25, zero halo/pad ----
    const unsigned short* ib = inp + (size_t)b*IPB;
    for (int idx = tid; idx < 2160; idx += 512){
        int q   = idx/216, pix = idx - q*216;
        int rr  = pix/27,  cc  = pix - rr*27;
        int gr  = r0row - 1 + rr, gc = cc - 1;
        float4 v = {0.f,0.f,0.f,0.f};
        if ((unsigned)gr < 25u && (unsigned)gc < 25u)
            v = *reinterpret_cast<const float4*>(ib + (((size_t)q*PLANE + gr*25 + gc)<<3));
        *reinterpret_cast<float4*>(at2 + ((size_t)idx<<3)) = v;
    }

    // per-lane m-tile pixel bases (A row = lane&31 within m-tile)
    const int kh = lane >> 5;
    const unsigned short* ap[4];
    #pragma unroll
    for (int mt = 0; mt < 4; ++mt){
        int m = mg*128 + mt*32 + (lane & 31);
        int row = m/25, col = m - row*25;
        int pm = (row - r0row + 1)*27 + col;       // in [27, 213]
        ap[mt] = at2 + ((kh*216 + pm - 27) << 3);  // rebased so tap offsets >= 0
    }

    f32x16 acc[4];
    #pragma unroll
    for (int mt = 0; mt < 4; ++mt)
        #pragma unroll
        for (int e = 0; e < 16; ++e) acc[mt][e] = 0.f;

    __syncthreads();

    // ---- K loop: 9 taps x 5 ci ----
    const bf16x8* wptr = reinterpret_cast<const bf16x8*>(wpk) + nt*64 + lane;
    bf16x8 bcur = *wptr;
    const unsigned short *a0 = ap[0], *a1 = ap[1], *a2 = ap[2], *a3 = ap[3];
    #pragma unroll 1
    for (int tap = 0; tap < 9; ++tap){
        #pragma unroll
        for (int ci = 0; ci < 5; ++ci){
            bf16x8 bnxt = wptr[512];               // 1-deep prefetch (last reads slack)
            wptr += 512;
            bf16x8 f0 = *reinterpret_cast<const bf16x8*>(a0 + ci*3456);  // imm offsets
            bf16x8 f1 = *reinterpret_cast<const bf16x8*>(a1 + ci*3456);
            bf16x8 f2 = *reinterpret_cast<const bf16x8*>(a2 + ci*3456);
            bf16x8 f3 = *reinterpret_cast<const bf16x8*>(a3 + ci*3456);
            acc[0] = __builtin_amdgcn_mfma_f32_32x32x16_bf16(f0, bcur, acc[0], 0,0,0);
            acc[1] = __builtin_amdgcn_mfma_f32_32x32x16_bf16(f1, bcur, acc[1], 0,0,0);
            acc[2] = __builtin_amdgcn_mfma_f32_32x32x16_bf16(f2, bcur, acc[2], 0,0,0);
            acc[3] = __builtin_amdgcn_mfma_f32_32x32x16_bf16(f3, bcur, acc[3], 0,0,0);
            bcur = bnxt;
        }
        const int d = (tap == 2 || tap == 5) ? 25*8 : 8;   // toff delta in shorts
        a0 += d; a1 += d; a2 += d; a3 += d;
    }

    // ---- fused LSTM epilogue: quad transpose -> all lanes update ----
    const int g   = lane & 3;
    const int jlo = (lane & 31) >> 2;
    const int j   = nt*8 + jlo;
    const float bown = bias[g*64 + j];
    const float sA = (g == 3) ? 2.f : 1.f;    // act = sA*sigm(sA*x) + sB (tanh when g=3)
    const float sB = (g == 3) ? -1.f : 0.f;
    const int  mbase = mg*128 + 4*kh;
    const bool gb0 = (g & 1), gb1 = (g & 2);
    float* cb = cbuf + (size_t)b*PLANE*HID;
    float* hb = hbuf + (size_t)b*PLANE*HID;
    unsigned short* hn = inpn + (size_t)b*IPB;
    const int chh = CIN + j, uh = chh >> 3, sh = chh & 7;

    #pragma unroll
    for (int mt = 0; mt < 4; ++mt){
        #pragma unroll
        for (int rq = 0; rq < 4; ++rq){
            float v0 = fmaf(sA, fsigm(sA*(acc[mt][rq*4+0] + bown)), sB);
            float v1 = fmaf(sA, fsigm(sA*(acc[mt][rq*4+1] + bown)), sB);
            float v2 = fmaf(sA, fsigm(sA*(acc[mt][rq*4+2] + bown)), sB);
            float v3 = fmaf(sA, fsigm(sA*(acc[mt][rq*4+3] + bown)), sB);
            float s;
            s = __shfl_xor(gb0 ? v0 : v1, 1); if (gb0) v0 = s; else v1 = s;
            s = __shfl_xor(gb0 ? v2 : v3, 1); if (gb0) v2 = s; else v3 = s;
            s = __shfl_xor(gb1 ? v0 : v2, 2); if (gb1) v0 = s; else v2 = s;
            s = __shfl_xor(gb1 ? v1 : v3, 2); if (gb1) v1 = s; else v3 = s;
            // now v0=i, v1=f, v2=o, v3=g~ of element m below
            const int m = mbase + mt*32 + g + 8*rq;
            if (m < PLANE){
                float co = cb[m*HID + j];
                float cn = fmaf(v1, co, v0*v3);
                float h  = v2 * ftanh(cn);
                cb[m*HID + j] = cn;
                hn[((uh*PLANE + m) << 3) + sh] = f2bf(h);
                if (t == TT-1) hb[m*HID + j] = h;
            }
        }
    }

    // ---- fused x-copy for step t+1 (this block's m-slice) ----
    if (t < TT-1){
        const float* xn = x + (size_t)(b*TT + t + 1)*CIN*PLANE;
        for (int idx = tid; idx < 1280; idx += 512){
            int ch = idx >> 7, mi = idx & 127;
            int m = mg*128 + mi;
            if (m < PLANE)
                inpn[(size_t)b*IPB + ((((ch>>3)*PLANE) + m)<<3) + (ch&7)] =
                    f2bf(xn[ch*PLANE + m]);
        }
    }
}

// -------- MLP stage 1: partial h@w1 over k-split (w1-major, coalesced) --------
// grid (KSPLIT, BATCH), 256 thr. kw = j*625 + m (w1 row index); h layout [b][m][j].
// Wave butterfly-reduce 16 accs, cross-wave via LDS; partials -> part[b][ks][16].
__global__ __launch_bounds__(256) void k_mlp1(
    const float* __restrict__ hfin, const float* __restrict__ w1,
    float* __restrict__ part)
{
    __shared__ float xw[4][16];
    const int ks = blockIdx.x, b = blockIdx.y, tid = threadIdx.x;
    const float* hbb = hfin + (size_t)b * (HID * PLANE);

    float acc[16];
    #pragma unroll
    for (int i = 0; i < 16; ++i) acc[i] = 0.f;

    const int kw0 = ks * 4000, kw1 = kw0 + 4000;   // KSPLIT*4000 = 40000
    for (int kw = kw0 + tid; kw < kw1; kw += 256){
        int j = kw / 625, m = kw - j * 625;
        float hv = hbb[m * 64 + j];
        hv = hv > 0.f ? hv : 0.f;
        const float4* wf = (const float4*)(w1 + (size_t)kw * 16);  // 64B coalesced rows
        float4 wa = wf[0], wb = wf[1], wc = wf[2], wd = wf[3];
        acc[ 0] = fmaf(hv, wa.x, acc[ 0]); acc[ 1] = fmaf(hv, wa.y, acc[ 1]);
        acc[ 2] = fmaf(hv, wa.z, acc[ 2]); acc[ 3] = fmaf(hv, wa.w, acc[ 3]);
        acc[ 4] = fmaf(hv, wb.x, acc[ 4]); acc[ 5] = fmaf(hv, wb.y, acc[ 5]);
        acc[ 6] = fmaf(hv, wb.z, acc[ 6]); acc[ 7] = fmaf(hv, wb.w, acc[ 7]);
        acc[ 8] = fmaf(hv, wc.x, acc[ 8]); acc[ 9] = fmaf(hv, wc.y, acc[ 9]);
        acc[10] = fmaf(hv, wc.z, acc[10]); acc[11] = fmaf(hv, wc.w, acc[11]);
        acc[12] = fmaf(hv, wd.x, acc[12]); acc[13] = fmaf(hv, wd.y, acc[13]);
        acc[14] = fmaf(hv, wd.z, acc[14]); acc[15] = fmaf(hv, wd.w, acc[15]);
    }
    // 64-lane butterfly reduce
    #pragma unroll
    for (int d = 1; d < 64; d <<= 1)
        #pragma unroll
        for (int i = 0; i < 16; ++i) acc[i] += __shfl_xor(acc[i], d);
    if ((tid & 63) == 0)
        #pragma unroll
        for (int i = 0; i < 16; ++i) xw[tid >> 6][i] = acc[i];
    __syncthreads();
    if (tid < 16)
        part[((size_t)b * KSPLIT + ks) * 16 + tid] =
            xw[0][tid] + xw[1][tid] + xw[2][tid] + xw[3][tid];
}

// -------- MLP stage 2: fold partials, 16 -> 8 -> 2 -> log_softmax --------
__global__ __launch_bounds__(128) void k_mlp2(
    const float* __restrict__ part,
    const float* __restrict__ b1,
    const float* __restrict__ w2, const float* __restrict__ b2,
    const float* __restrict__ w3, const float* __restrict__ b3,
    float* __restrict__ out)
{
    const int b = threadIdx.x;                // one thread per batch row
    float h1[16];
    #pragma unroll
    for (int i = 0; i < 16; ++i) h1[i] = b1[i];
    for (int s = 0; s < KSPLIT; ++s)
        #pragma unroll
        for (int i = 0; i < 16; ++i) h1[i] += part[((size_t)b * KSPLIT + s) * 16 + i];
    #pragma unroll
    for (int i = 0; i < 16; ++i) h1[i] = h1[i] > 0.f ? h1[i] : 0.f;

    float h2[8];
    #pragma unroll
    for (int i = 0; i < 8; ++i){
        float s2 = b2[i];
        #pragma unroll
        for (int k2 = 0; k2 < 16; ++k2) s2 += h1[k2] * w2[k2*8 + i];
        h2[i] = s2 > 0.f ? s2 : 0.f;
    }
    float l0 = b3[0], l1 = b3[1];
    #pragma unroll
    for (int k3 = 0; k3 < 8; ++k3){ l0 += h2[k3]*w3[k3*2]; l1 += h2[k3]*w3[k3*2+1]; }
    float m   = fmaxf(l0, l1);
    float lse = m + logf(__expf(l0 - m) + __expf(l1 - m));
    out[b*2 + 0] = l0 - lse;
    out[b*2 + 1] = l1 - lse;
}

extern "C" void kernel_launch(void* const* d_in, const int* in_sizes, int n_in,
                              void* d_out, int out_size, void* d_ws, size_t ws_size,
                              hipStream_t stream) {
    const float* x      = (const float*)d_in[0];
    const float* conv_w = (const float*)d_in[1];
    const float* conv_b = (const float*)d_in[2];
    const float* w1     = (const float*)d_in[3];
    const float* b1     = (const float*)d_in[4];
    const float* w2     = (const float*)d_in[5];
    const float* b2     = (const float*)d_in[6];
    const float* w3     = (const float*)d_in[7];
    const float* b3     = (const float*)d_in[8];
    float* out = (float*)d_out;

    // ws carve (~67 MB): inp0/inp1 bf16 12.8MB each, c 20.5MB, h 20.5MB, wpk 0.38MB, part 80KB
    unsigned short* inp0 = (unsigned short*)d_ws;
    unsigned short* inp1 = inp0 + (size_t)BATCH*IPB;
    float* c   = (float*)(inp1 + (size_t)BATCH*IPB);
    float* hb  = c + CSZ;
    unsigned short* wpk = (unsigned short*)(hb + CSZ);   // NKB frags + 1 slack frag
    float* part = (float*)(wpk + (size_t)(NKB+1)*8*64*8);

    // ws poisoned 0xAA, not re-poisoned between replays -> re-init every call
    hipMemsetAsync(inp0, 0, (size_t)BATCH*IPB*2, stream);   // zeros h(t=0) + ch pad
    hipMemsetAsync(inp1, 0, (size_t)BATCH*IPB*2, stream);   // zeros ch pad
    hipMemsetAsync(c,    0, (size_t)CSZ*4,       stream);

    k_wprep<<<dim3(90),   dim3(256), 0, stream>>>(conv_w, wpk);
    k_xcopy<<<dim3(3125), dim3(256), 0, stream>>>(x, inp0, 0);

    for (int t = 0; t < TT; ++t){
        unsigned short* ic  = (t & 1) ? inp1 : inp0;
        unsigned short* in_ = (t & 1) ? inp0 : inp1;
        k_gemm<<<dim3(5, BATCH), dim3(512), 0, stream>>>(x, ic, in_, wpk, conv_b, c, hb, t);
    }
    k_mlp1<<<dim3(KSPLIT, BATCH), dim3(256), 0, stream>>>(hb, w1, part);
    k_mlp2<<<dim3(1), dim3(128), 0, stream>>>(part, b1, w2, b2, w3, b3, out);
}

// Round 9
// 624.483 us; speedup vs baseline: 1.1735x; 1.1735x over previous
//
#include <hip/hip_runtime.h>
#include <hip/hip_bf16.h>
#include <math.h>

#define BATCH 128
#define TT    12
#define CIN   10
#define HID   64
#define PLANE 625
#define NU    10          // 16B channel-units per pixel (80 padded ch)
#define IPB   50000       // shorts per batch image in inp: NU*PLANE*8
#define NKB   45          // k-blocks: 9 taps * 5 chunks of 16 ch
#define CSZ   (BATCH*PLANE*HID)   // floats in c buffer
#define KSPLIT 10         // k_mlp1 k-dimension splits (40000/10 = 4000 per block)

typedef __attribute__((ext_vector_type(8)))  short bf16x8;
typedef __attribute__((ext_vector_type(16))) float f32x16;

__device__ __forceinline__ float fsigm(float v){ return 1.f/(1.f+__expf(-v)); }
__device__ __forceinline__ float ftanh(float v){ return 1.f - 2.f/(__expf(2.f*v)+1.f); }
__device__ __forceinline__ unsigned short f2bf(float v){
    __hip_bfloat16 b = __float2bfloat16(v);
    return *reinterpret_cast<unsigned short*>(&b);
}

// ---- prepack conv_w (256,74,3,3) f32 -> B-fragments bf16 ----
// k = tap*80 + ch (tap = ky*3+kx), n-permutation: col = jlo*4 + g  (j = nt*8+jlo, o = g*64+j)
// frag layout (32x32x16 B): lane l: col = l&31, k_local = (l>>5)*8 + e
__global__ void k_wprep(const float* __restrict__ w, unsigned short* __restrict__ wpk){
    int tid = blockIdx.x*256 + threadIdx.x;      // NKB*8*64 = 23040 total
    if (tid >= NKB*8*64) return;
    int lane = tid & 63;
    int nt   = (tid >> 6) & 7;
    int kb   = tid >> 9;
    int tap = kb/5, ci = kb - tap*5;
    int ky = tap/3, kx = tap - ky*3;
    int g = lane & 3, jlo = (lane & 31) >> 2, kh = lane >> 5;
    int o = g*64 + nt*8 + jlo;
    union { unsigned short u[8]; float4 f; } pk;
    #pragma unroll
    for (int e = 0; e < 8; ++e){
        int ch = ci*16 + kh*8 + e;
        float v = (ch < 74) ? w[((o*74 + ch)*3 + ky)*3 + kx] : 0.f;
        pk.u[e] = f2bf(v);
    }
    *reinterpret_cast<float4*>(wpk + (size_t)tid*8) = pk.f;   // idx = (kb*8+nt)*64+lane
}

// ---- transpose w1 (40000=j*625+m rows, 16 cols) -> w1t rows k' = m*64+j ----
__global__ void k_w1prep(const float* __restrict__ w1, float* __restrict__ w1t){
    int tid = blockIdx.x*256 + threadIdx.x;      // 40000*4
    if (tid >= 40000*4) return;
    int rowp = tid >> 2, f4 = tid & 3;
    int m = rowp >> 6, j = rowp & 63;
    const float4* src = (const float4*)(w1 + (size_t)(j*625 + m)*16);
    ((float4*)(w1t + (size_t)rowp*16))[f4] = src[f4];
}

// ---- copy x_0 (f32 NCHW) into inp buffer x-slots (unit-major bf16 layout) ----
__global__ void k_xcopy(const float* __restrict__ x, unsigned short* __restrict__ inp, int t){
    int idx = blockIdx.x*256 + threadIdx.x;      // 128*10*625 = 800000
    if (idx >= BATCH*CIN*PLANE) return;
    int m  = idx % PLANE;
    int r  = idx / PLANE;
    int ch = r % CIN;
    int b  = r / CIN;
    float v = x[((size_t)(b*TT + t)*CIN + ch)*PLANE + m];
    inp[(size_t)b*IPB + ((((ch>>3)*PLANE) + m)<<3) + (ch&7)] = f2bf(v);
}

// ---- fused conv-as-GEMM (MFMA bf16) + LSTM pointwise + next-step x-copy ----
// 64m x 256n blocks, grid (10 mg, 128 b) = 1280 blocks, 8 waves (wave = n-tile, 2 m-tiles).
// 25.9KB LDS + 32-reg acc -> 4 blocks/CU = 32 waves/CU (round-8 post-mortem: 28%
// occupancy left k_gemm latency-stall-bound at ~3x its component floors).
// A-tile LDS [u][162 pix][8]: conflict-free ds_read_b128; K-loop ci-unrolled with
// immediate offsets, tap loop unroll-1 with constant pointer increments; B via walking
// pointer + 1-deep prefetch. Epilogue: quad transpose -> all 64 lanes do c-updates.
__global__ __launch_bounds__(512) void k_gemm(
    const float* __restrict__ x,
    const unsigned short* __restrict__ inp,   // step-t input, unit-major
    unsigned short* __restrict__ inpn,        // next-step buffer (h-part + x-part writes)
    const unsigned short* __restrict__ wpk,
    const float* __restrict__ bias,           // conv_b[256], o = g*64+j
    float* __restrict__ cbuf,                 // [b][625][64] fp32
    unsigned short* __restrict__ hbf,         // [b][m*64+j] relu'd bf16 h (t=TT-1 only)
    int t)
{
    __shared__ __align__(16) unsigned short at2[1620*8];   // [10 u][6r*27c][8], 25.92 KB

    const int tid  = threadIdx.x;
    const int mg   = blockIdx.x;              // 0..9 (64 m each; m 625..639 pad)
    const int b    = blockIdx.y;
    const int lane = tid & 63;
    const int nt   = tid >> 6;                // wave id = n-tile
    const int rlo  = (mg*64)/25;              // first output row of this m-group

    // ---- stage A-tile: rows rlo-1..rlo+4, cols -1..25, zero halo/pad ----
    const unsigned short* ib = inp + (size_t)b*IPB;
    for (int idx = tid; idx < 1620; idx += 512){
        int q   = idx/162, pix = idx - q*162;
        int rr  = pix/27,  cc  = pix - rr*27;
        int gr  = rlo - 1 + rr, gc = cc - 1;
        float4 v = {0.f,0.f,0.f,0.f};
        if ((unsigned)gr < 25u && (unsigned)gc < 25u)
            v = *reinterpret_cast<const float4*>(ib + (((size_t)q*PLANE + gr*25 + gc)<<3));
        *reinterpret_cast<float4*>(at2 + ((size_t)idx<<3)) = v;
    }

    // per-lane m-tile pixel bases (A row = lane&31 within m-tile)
    const int kh = lane >> 5;
    const unsigned short* ap[2];
    #pragma unroll
    for (int mt = 0; mt < 2; ++mt){
        int m = mg*64 + mt*32 + (lane & 31);
        int row = m/25, col = m - row*25;
        int pm = (row - rlo + 1)*27 + col;         // in [27, 161]
        ap[mt] = at2 + kh*1296 + ((pm - 27) << 3); // rebased so tap offsets >= 0
    }

    f32x16 acc[2];
    #pragma unroll
    for (int mt = 0; mt < 2; ++mt)
        #pragma unroll
        for (int e = 0; e < 16; ++e) acc[mt][e] = 0.f;

    __syncthreads();

    // ---- K loop: 9 taps x 5 ci (ci stride = 2 units = 2592 shorts) ----
    const bf16x8* wptr = reinterpret_cast<const bf16x8*>(wpk) + nt*64 + lane;
    bf16x8 bcur = *wptr;
    const unsigned short *a0 = ap[0], *a1 = ap[1];
    #pragma unroll 1
    for (int tap = 0; tap < 9; ++tap){
        #pragma unroll
        for (int ci = 0; ci < 5; ++ci){
            bf16x8 bnxt = wptr[512];               // 1-deep prefetch (last reads slack)
            wptr += 512;
            bf16x8 f0 = *reinterpret_cast<const bf16x8*>(a0 + ci*2592);  // imm offsets
            bf16x8 f1 = *reinterpret_cast<const bf16x8*>(a1 + ci*2592);
            acc[0] = __builtin_amdgcn_mfma_f32_32x32x16_bf16(f0, bcur, acc[0], 0,0,0);
            acc[1] = __builtin_amdgcn_mfma_f32_32x32x16_bf16(f1, bcur, acc[1], 0,0,0);
            bcur = bnxt;
        }
        const int d = (tap == 2 || tap == 5) ? 25*8 : 8;   // pixel-walk delta in shorts
        a0 += d; a1 += d;
    }

    // ---- fused LSTM epilogue: quad transpose -> all lanes update ----
    const int g   = lane & 3;
    const int jlo = (lane & 31) >> 2;
    const int j   = nt*8 + jlo;
    const float bown = bias[g*64 + j];
    const float sA = (g == 3) ? 2.f : 1.f;    // act = sA*sigm(sA*x) + sB (tanh when g=3)
    const float sB = (g == 3) ? -1.f : 0.f;
    const int  mbase = mg*64 + 4*kh;
    const bool gb0 = (g & 1), gb1 = (g & 2);
    float* cb = cbuf + (size_t)b*PLANE*HID;
    unsigned short* hn  = inpn + (size_t)b*IPB;
    unsigned short* hfb = hbf  + (size_t)b*40000;
    const int chh = CIN + j, uh = chh >> 3, sh = chh & 7;

    #pragma unroll
    for (int mt = 0; mt < 2; ++mt){
        #pragma unroll
        for (int rq = 0; rq < 4; ++rq){
            float v0 = fmaf(sA, fsigm(sA*(acc[mt][rq*4+0] + bown)), sB);
            float v1 = fmaf(sA, fsigm(sA*(acc[mt][rq*4+1] + bown)), sB);
            float v2 = fmaf(sA, fsigm(sA*(acc[mt][rq*4+2] + bown)), sB);
            float v3 = fmaf(sA, fsigm(sA*(acc[mt][rq*4+3] + bown)), sB);
            float s;
            s = __shfl_xor(gb0 ? v0 : v1, 1); if (gb0) v0 = s; else v1 = s;
            s = __shfl_xor(gb0 ? v2 : v3, 1); if (gb0) v2 = s; else v3 = s;
            s = __shfl_xor(gb1 ? v0 : v2, 2); if (gb1) v0 = s; else v2 = s;
            s = __shfl_xor(gb1 ? v1 : v3, 2); if (gb1) v1 = s; else v3 = s;
            // now v0=i, v1=f, v2=o, v3=g~ of element m below
            const int m = mbase + mt*32 + g + 8*rq;
            if (m < PLANE){
                float co = cb[m*HID + j];
                float cn = fmaf(v1, co, v0*v3);
                float h  = v2 * ftanh(cn);
                if (t < TT-1){
                    cb[m*HID + j] = cn;
                    hn[((uh*PLANE + m) << 3) + sh] = f2bf(h);
                } else {
                    hfb[m*64 + j] = f2bf(h > 0.f ? h : 0.f);   // relu'd, MLP-ready
                }
            }
        }
    }

    // ---- fused x-copy for step t+1 (this block's m-slice) ----
    if (t < TT-1){
        const float* xn = x + (size_t)(b*TT + t + 1)*CIN*PLANE;
        for (int idx = tid; idx < 640; idx += 512){
            int ch = idx >> 6, mi = idx & 63;
            int m = mg*64 + mi;
            if (m < PLANE)
                inpn[(size_t)b*IPB + ((((ch>>3)*PLANE) + m)<<3) + (ch&7)] =
                    f2bf(xn[ch*PLANE + m]);
        }
    }
}

// -------- MLP stage 1: partial h@w1, coalesced bf16 h + transposed w1 --------
// grid (KSPLIT, 32 batch-groups), 256 thr. Block: k'-slice of 4000 x 4 batches;
// w1t rows held in registers and reused across the 4 batches (kills the 220MB
// over-fetch of round 8: h now unit-stride, w1t L2-resident read once per block).
__global__ __launch_bounds__(256) void k_mlp1(
    const unsigned short* __restrict__ hbf, const float* __restrict__ w1t,
    float* __restrict__ part)
{
    __shared__ float xw[4][4][16];
    const int ks = blockIdx.x, bg = blockIdx.y, tid = threadIdx.x;
    const int kw0 = ks*4000, kw1 = kw0 + 4000;
    const unsigned short* h0 = hbf + (size_t)(bg*4+0)*40000;
    const unsigned short* h1 = hbf + (size_t)(bg*4+1)*40000;
    const unsigned short* h2 = hbf + (size_t)(bg*4+2)*40000;
    const unsigned short* h3 = hbf + (size_t)(bg*4+3)*40000;

    float acc[4][16];
    #pragma unroll
    for (int bi = 0; bi < 4; ++bi)
        #pragma unroll
        for (int n = 0; n < 16; ++n) acc[bi][n] = 0.f;

    for (int kw = kw0 + tid*2; kw < kw1; kw += 512){
        const float4* wp = (const float4*)(w1t + (size_t)kw*16);   // rows kw, kw+1
        float4 q0 = wp[0], q1 = wp[1], q2 = wp[2], q3 = wp[3];
        float4 r0 = wp[4], r1 = wp[5], r2 = wp[6], r3 = wp[7];
        unsigned int u0 = *(const unsigned int*)(h0 + kw);
        unsigned int u1 = *(const unsigned int*)(h1 + kw);
        unsigned int u2 = *(const unsigned int*)(h2 + kw);
        unsigned int u3 = *(const unsigned int*)(h3 + kw);
        #define ACC1(bi, u) { \
            float fl = __uint_as_float((u) << 16); \
            float fh = __uint_as_float((u) & 0xffff0000u); \
            acc[bi][ 0]=fmaf(fl,q0.x,fmaf(fh,r0.x,acc[bi][ 0])); \
            acc[bi][ 1]=fmaf(fl,q0.y,fmaf(fh,r0.y,acc[bi][ 1])); \
            acc[bi][ 2]=fmaf(fl,q0.z,fmaf(fh,r0.z,acc[bi][ 2])); \
            acc[bi][ 3]=fmaf(fl,q0.w,fmaf(fh,r0.w,acc[bi][ 3])); \
            acc[bi][ 4]=fmaf(fl,q1.x,fmaf(fh,r1.x,acc[bi][ 4])); \
            acc[bi][ 5]=fmaf(fl,q1.y,fmaf(fh,r1.y,acc[bi][ 5])); \
            acc[bi][ 6]=fmaf(fl,q1.z,fmaf(fh,r1.z,acc[bi][ 6])); \
            acc[bi][ 7]=fmaf(fl,q1.w,fmaf(fh,r1.w,acc[bi][ 7])); \
            acc[bi][ 8]=fmaf(fl,q2.x,fmaf(fh,r2.x,acc[bi][ 8])); \
            acc[bi][ 9]=fmaf(fl,q2.y,fmaf(fh,r2.y,acc[bi][ 9])); \
            acc[bi][10]=fmaf(fl,q2.z,fmaf(fh,r2.z,acc[bi][10])); \
            acc[bi][11]=fmaf(fl,q2.w,fmaf(fh,r2.w,acc[bi][11])); \
            acc[bi][12]=fmaf(fl,q3.x,fmaf(fh,r3.x,acc[bi][12])); \
            acc[bi][13]=fmaf(fl,q3.y,fmaf(fh,r3.y,acc[bi][13])); \
            acc[bi][14]=fmaf(fl,q3.z,fmaf(fh,r3.z,acc[bi][14])); \
            acc[bi][15]=fmaf(fl,q3.w,fmaf(fh,r3.w,acc[bi][15])); }
        ACC1(0, u0) ACC1(1, u1) ACC1(2, u2) ACC1(3, u3)
        #undef ACC1
    }

    // 64-lane butterfly reduce per batch, then cross-wave via LDS
    #pragma unroll
    for (int d = 1; d < 64; d <<= 1)
        #pragma unroll
        for (int bi = 0; bi < 4; ++bi)
            #pragma unroll
            for (int n = 0; n < 16; ++n) acc[bi][n] += __shfl_xor(acc[bi][n], d);
    if ((tid & 63) == 0){
        int w = tid >> 6;
        #pragma unroll
        for (int bi = 0; bi < 4; ++bi)
            #pragma unroll
            for (int n = 0; n < 16; ++n) xw[w][bi][n] = acc[bi][n];
    }
    __syncthreads();
    if (tid < 64){
        int bi = tid >> 4, n = tid & 15;
        float s = xw[0][bi][n] + xw[1][bi][n] + xw[2][bi][n] + xw[3][bi][n];
        part[((size_t)(bg*4 + bi)*KSPLIT + ks)*16 + n] = s;
    }
}

// -------- MLP stage 2: fold partials, 16 -> 8 -> 2 -> log_softmax --------
__global__ __launch_bounds__(128) void k_mlp2(
    const float* __restrict__ part,
    const float* __restrict__ b1,
    const float* __restrict__ w2, const float* __restrict__ b2,
    const float* __restrict__ w3, const float* __restrict__ b3,
    float* __restrict__ out)
{
    const int b = threadIdx.x;                // one thread per batch row
    float h1[16];
    #pragma unroll
    for (int i = 0; i < 16; ++i) h1[i] = b1[i];
    for (int s = 0; s < KSPLIT; ++s)
        #pragma unroll
        for (int i = 0; i < 16; ++i) h1[i] += part[((size_t)b * KSPLIT + s) * 16 + i];
    #pragma unroll
    for (int i = 0; i < 16; ++i) h1[i] = h1[i] > 0.f ? h1[i] : 0.f;

    float h2[8];
    #pragma unroll
    for (int i = 0; i < 8; ++i){
        float s2 = b2[i];
        #pragma unroll
        for (int k2 = 0; k2 < 16; ++k2) s2 += h1[k2] * w2[k2*8 + i];
        h2[i] = s2 > 0.f ? s2 : 0.f;
    }
    float l0 = b3[0], l1 = b3[1];
    #pragma unroll
    for (int k3 = 0; k3 < 8; ++k3){ l0 += h2[k3]*w3[k3*2]; l1 += h2[k3]*w3[k3*2+1]; }
    float m   = fmaxf(l0, l1);
    float lse = m + logf(__expf(l0 - m) + __expf(l1 - m));
    out[b*2 + 0] = l0 - lse;
    out[b*2 + 1] = l1 - lse;
}

extern "C" void kernel_launch(void* const* d_in, const int* in_sizes, int n_in,
                              void* d_out, int out_size, void* d_ws, size_t ws_size,
                              hipStream_t stream) {
    const float* x      = (const float*)d_in[0];
    const float* conv_w = (const float*)d_in[1];
    const float* conv_b = (const float*)d_in[2];
    const float* w1     = (const float*)d_in[3];
    const float* b1     = (const float*)d_in[4];
    const float* w2     = (const float*)d_in[5];
    const float* b2     = (const float*)d_in[6];
    const float* w3     = (const float*)d_in[7];
    const float* b3     = (const float*)d_in[8];
    float* out = (float*)d_out;

    // ws carve (~59.5 MB): inp0/inp1 12.8MB, c 20.5MB, hbf 10.25MB, wpk .37MB, w1t 2.56MB
    unsigned short* inp0 = (unsigned short*)d_ws;
    unsigned short* inp1 = inp0 + (size_t)BATCH*IPB;
    float* c   = (float*)(inp1 + (size_t)BATCH*IPB);
    unsigned short* hbf = (unsigned short*)(c + CSZ);
    unsigned short* wpk = hbf + (size_t)BATCH*40000;     // NKB frags + 1 slack frag
    float* w1t  = (float*)(wpk + (size_t)(NKB+1)*8*64*8);
    float* part = w1t + 640000;

    // ws poisoned 0xAA, not re-poisoned between replays -> re-init every call
    hipMemsetAsync(inp0, 0, (size_t)BATCH*IPB*2, stream);   // zeros h(t=0) + ch pad
    hipMemsetAsync(inp1, 0, (size_t)BATCH*IPB*2, stream);   // zeros ch pad
    hipMemsetAsync(c,    0, (size_t)CSZ*4,       stream);

    k_wprep <<<dim3(90),   dim3(256), 0, stream>>>(conv_w, wpk);
    k_w1prep<<<dim3(625),  dim3(256), 0, stream>>>(w1, w1t);
    k_xcopy <<<dim3(3125), dim3(256), 0, stream>>>(x, inp0, 0);

    for (int t = 0; t < TT; ++t){
        unsigned short* ic  = (t & 1) ? inp1 : inp0;
        unsigned short* in_ = (t & 1) ? inp0 : inp1;
        k_gemm<<<dim3(10, BATCH), dim3(512), 0, stream>>>(x, ic, in_, wpk, conv_b, c, hbf, t);
    }
    k_mlp1<<<dim3(KSPLIT, 32), dim3(256), 0, stream>>>(hbf, w1t, part);
    k_mlp2<<<dim3(1), dim3(128), 0, stream>>>(part, b1, w2, b2, w3, b3, out);
}